// Round 14
// baseline (243.052 us; speedup 1.0000x reference)
//
#include <hip/hip_runtime.h>
#include <hip/hip_bf16.h>

typedef unsigned short u16;
typedef __bf16 bf16x8 __attribute__((ext_vector_type(8)));
typedef u16 u16x8 __attribute__((ext_vector_type(8)));
typedef float f32x4 __attribute__((ext_vector_type(4)));

__device__ __forceinline__ float bf2f(u16 u) {
    return __uint_as_float(((unsigned)u) << 16);
}
__device__ __forceinline__ u16 f2bf(float f) {
    unsigned u = __float_as_uint(f);
    unsigned r = (u + 0x7fffu + ((u >> 16) & 1u)) >> 16;
    return (u16)r;
}

// async global->LDS, 16B per lane. dst is wave-uniform base; HW adds lane*16.
__device__ __forceinline__ void gl_lds16(const u16* g, u16* l) {
    __builtin_amdgcn_global_load_lds(
        (const __attribute__((address_space(1))) void*)g,
        (__attribute__((address_space(3))) void*)l, 16, 0, 0);
}

// ---------------- fused prep: x f32->bf16 convert + 3 weight transposes ----------------
// blocks [0,10280): convert x; [10280,+64): WvTv (Wv cols 1024:1536);
// [+64,+256): WaT; [+256,+320): WoT.
__global__ __launch_bounds__(256) void prep(const float* __restrict__ x,
                                            const float* __restrict__ Wv,
                                            const float* __restrict__ Wa,
                                            const float* __restrict__ Wo,
                                            u16* __restrict__ xb,
                                            u16* __restrict__ WvTv,
                                            u16* __restrict__ WaT,
                                            u16* __restrict__ WoT) {
    __shared__ float tile[64][65];
    int blk = blockIdx.x;
    if (blk < 10280) {
        int i = (blk * 256 + threadIdx.x) * 8;
        float4 a = *(const float4*)&x[i];
        float4 b = *(const float4*)&x[i + 4];
        u16x8 o;
        o[0] = f2bf(a.x); o[1] = f2bf(a.y); o[2] = f2bf(a.z); o[3] = f2bf(a.w);
        o[4] = f2bf(b.x); o[5] = f2bf(b.y); o[6] = f2bf(b.z); o[7] = f2bf(b.w);
        *(u16x8*)&xb[i] = o;
        return;
    }
    blk -= 10280;
    const float* W; u16* WT; int N, stride, coff;
    if (blk < 64)       { W = Wv; WT = WvTv; N = 512;  stride = 1536; coff = 1024; }
    else if (blk < 256) { W = Wa; WT = WaT;  N = 1536; stride = 1536; coff = 0; blk -= 64; }
    else                { W = Wo; WT = WoT;  N = 512;  stride = 512;  coff = 0; blk -= 256; }
    const int nt = N >> 6;
    const int k0 = (blk / nt) << 6;
    const int n0 = (blk % nt) << 6;
    for (int i = threadIdx.x; i < 4096; i += 256) {
        int r = i >> 6, c = i & 63;
        tile[r][c] = W[(size_t)(k0 + r) * stride + coff + n0 + c];
    }
    __syncthreads();
    for (int i = threadIdx.x; i < 4096; i += 256) {
        int r = i >> 6, c = i & 63;
        WT[(size_t)(n0 + r) * 512 + k0 + c] = f2bf(tile[c][r]);
    }
}

// ---------------- small m97-style GEMM (A-projection) ----------
// MODE 2: row r -> r*257 (clamp r<M).
template <int MODE, int OUTF>
__global__ __launch_bounds__(256) void gemm_k(const u16* __restrict__ A,
                                              const u16* __restrict__ Bt,
                                              void* __restrict__ Cv,
                                              const float* __restrict__ bias,
                                              int M, int N, int K) {
    __shared__ u16 As[128][64];
    __shared__ u16 Bs[128][64];
    const int t = threadIdx.x;
    const int bn0 = blockIdx.x * 128;
    const int bm0 = blockIdx.y * 128;
    const int wave = t >> 6, lane = t & 63;
    const int wm = (wave >> 1) * 64, wn = (wave & 1) * 64;
    const int lr = lane & 15, lh = lane >> 4;
    const int srow = wave * 8 + (lane >> 3);
    const int scol = (lane & 7) * 8;

    f32x4 acc[4][4] = {};

    for (int kt = 0; kt < K; kt += 64) {
        __syncthreads();
#pragma unroll
        for (int i = 0; i < 4; i++) {
            int row = i * 32 + srow;
            int r = bm0 + row;
            long g;
            if (MODE == 0) g = (r < M) ? (long)r : 0l;
            else           g = (r < M) ? (long)r * 257 : 0l;
            gl_lds16(&A[g * K + kt + scol], &As[0][0] + i * 2048 + wave * 512);
            long nr = bn0 + row;
            gl_lds16(&Bt[nr * K + kt + scol], &Bs[0][0] + i * 2048 + wave * 512);
        }
        __syncthreads();
#pragma unroll
        for (int kk = 0; kk < 2; kk++) {
            bf16x8 af[4], bfr[4];
#pragma unroll
            for (int mi = 0; mi < 4; mi++)
                af[mi] = *(const bf16x8*)&As[wm + mi * 16 + lr][kk * 32 + lh * 8];
#pragma unroll
            for (int ni = 0; ni < 4; ni++)
                bfr[ni] = *(const bf16x8*)&Bs[wn + ni * 16 + lr][kk * 32 + lh * 8];
#pragma unroll
            for (int mi = 0; mi < 4; mi++)
#pragma unroll
                for (int ni = 0; ni < 4; ni++)
                    acc[mi][ni] = __builtin_amdgcn_mfma_f32_16x16x32_bf16(
                        af[mi], bfr[ni], acc[mi][ni], 0, 0, 0);
        }
    }

#pragma unroll
    for (int mi = 0; mi < 4; mi++)
#pragma unroll
        for (int ni = 0; ni < 4; ni++)
#pragma unroll
            for (int r2 = 0; r2 < 4; r2++) {
                int m = bm0 + wm + mi * 16 + lh * 4 + r2;
                if (m < M) {
                    int nc = bn0 + wn + ni * 16 + lr;
                    float v = acc[mi][ni][r2];
                    if (OUTF) ((float*)Cv)[(size_t)m * N + nc] = v + bias[nc];
                    else      ((u16*)Cv)[(size_t)m * N + nc] = f2bf(v);
                }
            }
}

// ---------------- pipelined 256x256 GEMM, K=512 (rounds 11-13 verified) ----------------
template <int MODE, int OUTF>
__global__ __launch_bounds__(1024) void gemm_big(const u16* __restrict__ A,
                                                 const u16* __restrict__ Bt,
                                                 void* __restrict__ Cv,
                                                 const float* __restrict__ bias,
                                                 int M, int N) {
    __shared__ u16 As[2][256][64];
    __shared__ u16 Bs[2][256][64];
    const int t = threadIdx.x;
    const int nwg = gridDim.x * gridDim.y;
    const int orig = blockIdx.y * gridDim.x + blockIdx.x;
    const int qc = nwg >> 3, rc = nwg & 7;
    const int xcd = orig & 7, slot = orig >> 3;
    const int wgid = (xcd < rc ? xcd * (qc + 1) : rc * (qc + 1) + (xcd - rc) * qc) + slot;
    const int bn0 = (wgid % gridDim.x) * 256;
    const int bm0 = (wgid / gridDim.x) * 256;
    const int wave = t >> 6, lane = t & 63;
    const int wm = (wave >> 2) * 64, wn = (wave & 3) * 64;
    const int lr = lane & 15, lh = lane >> 4;
    const int xr = (lr & 7) << 3;
    u16* AsF = &As[0][0][0];
    u16* BsF = &Bs[0][0][0];

    const int gsa = ((lane & 7) ^ (lane >> 3)) * 8;
    auto stage = [&](int buf, int kt_) {
        const int kc = kt_ * 64;
#pragma unroll
        for (int j = 0; j < 2; j++) {
            int c0 = j * 1024 + wave * 64;
            int row = (c0 + lane) >> 3;
            int r = bm0 + row;
            long ga;
            if (MODE == 0) ga = (r < M) ? (long)r : 0l;
            else           ga = (long)(r >> 8) * 257 + (r & 255) + 1;
            gl_lds16(&A[ga * 512 + kc + gsa], AsF + buf * 16384 + c0 * 8);
            gl_lds16(&Bt[(long)(bn0 + row) * 512 + kc + gsa], BsF + buf * 16384 + c0 * 8);
        }
    };

    f32x4 acc[4][4] = {};

    stage(0, 0);
    __builtin_amdgcn_sched_barrier(0);
    stage(1, 1);
    __builtin_amdgcn_sched_barrier(0);
    asm volatile("s_waitcnt vmcnt(0)" ::: "memory");
    __builtin_amdgcn_s_barrier();
    __builtin_amdgcn_sched_barrier(0);

    int cur = 0;
    for (int kt = 0; kt < 8; kt++) {
        __builtin_amdgcn_s_setprio(1);
#pragma unroll
        for (int kk = 0; kk < 2; kk++) {
            bf16x8 af[4], bfr[4];
#pragma unroll
            for (int mi = 0; mi < 4; mi++)
                af[mi] = *(const bf16x8*)&As[cur][wm + mi * 16 + lr][(kk * 32 + lh * 8) ^ xr];
#pragma unroll
            for (int ni = 0; ni < 4; ni++)
                bfr[ni] = *(const bf16x8*)&Bs[cur][wn + ni * 16 + lr][(kk * 32 + lh * 8) ^ xr];
#pragma unroll
            for (int mi = 0; mi < 4; mi++)
#pragma unroll
                for (int ni = 0; ni < 4; ni++)
                    acc[mi][ni] = __builtin_amdgcn_mfma_f32_16x16x32_bf16(
                        af[mi], bfr[ni], acc[mi][ni], 0, 0, 0);
        }
        __builtin_amdgcn_s_setprio(0);
        if (kt == 7) break;
        __builtin_amdgcn_sched_barrier(0);
        __builtin_amdgcn_s_barrier();
        __builtin_amdgcn_sched_barrier(0);
        if (kt + 2 < 8) {
            stage(cur, kt + 2);
            __builtin_amdgcn_sched_barrier(0);
            asm volatile("s_waitcnt vmcnt(4)" ::: "memory");
        } else {
            asm volatile("s_waitcnt vmcnt(0)" ::: "memory");
        }
        __builtin_amdgcn_sched_barrier(0);
        __builtin_amdgcn_s_barrier();
        __builtin_amdgcn_sched_barrier(0);
        cur ^= 1;
    }

#pragma unroll
    for (int mi = 0; mi < 4; mi++)
#pragma unroll
        for (int ni = 0; ni < 4; ni++)
#pragma unroll
            for (int r2 = 0; r2 < 4; r2++) {
                int m = bm0 + wm + mi * 16 + lh * 4 + r2;
                if (m < M) {
                    int nc = bn0 + wn + ni * 16 + lr;
                    float v = acc[mi][ni][r2];
                    if (OUTF) ((float*)Cv)[(size_t)m * N + nc] = v + bias[nc];
                    else      ((u16*)Cv)[(size_t)m * N + nc] = f2bf(v);
                }
            }
}

// ---------------- wbuild: w-tilde vectors ----------------
// wcomb[b][c][k], c = kind*40 + h*5 + q (rows 80..127 zero-padded).
// kind 0 (av): w = Wk_head @ qa  (Wv cols 512+h*64, aqkv off 0)
// kind 1 (va): w = Wq_head @ ka  (Wv cols h*64,     aqkv off 512)
// grid 136: blk<128 compute (kind=blk&1, h=(blk>>1)&7, vchunk=blk>>4); else pad-zero.
__global__ __launch_bounds__(512) void wbuild(const float* __restrict__ Wv,
                                              const u16* __restrict__ aqkv,
                                              u16* __restrict__ wcomb) {
    const int blk = blockIdx.x;
    const int t = threadIdx.x;
    if (blk >= 128) {
        const int base = blk - 128;          // 0..7 -> 4 b's each
        for (int bb = 0; bb < 4; bb++) {
            int b = base * 4 + bb;
            for (int i = t; i < 24576; i += 512)          // rows 80..127 contiguous
                wcomb[((size_t)b * 128 + 80) * 512 + i] = 0;
        }
        return;
    }
    __shared__ float avec[20][64];
    const int kind = blk & 1, h = (blk >> 1) & 7, vc = blk >> 4;
    const int v0 = vc * 20;
    const int aoff = (kind == 0) ? 0 : 512;
    for (int i = t; i < 1280; i += 512) {
        int vi = i >> 6, d = i & 63;
        int v = v0 + vi, b = v / 5, q = v - b * 5;
        avec[vi][d] = bf2f(aqkv[(size_t)(b * 5 + q) * 1536 + aoff + h * 64 + d]);
    }
    const int k = t;                                       // 0..511
    const int colbase = (kind == 0) ? (512 + h * 64) : (h * 64);
    float wr[64];
#pragma unroll
    for (int d = 0; d < 64; d += 4) {
        float4 w4 = *(const float4*)&Wv[(size_t)k * 1536 + colbase + d];
        wr[d] = w4.x; wr[d + 1] = w4.y; wr[d + 2] = w4.z; wr[d + 3] = w4.w;
    }
    __syncthreads();
    for (int vi = 0; vi < 20; vi++) {
        float acc = 0.f;
#pragma unroll
        for (int d = 0; d < 64; d++) acc += wr[d] * avec[vi][d];
        int v = v0 + vi, b = v / 5, q = v - b * 5;
        int c = kind * 40 + h * 5 + q;
        wcomb[((size_t)b * 128 + c) * 512 + k] = f2bf(acc);
    }
}

// ---------------- gemm_sc: scores GEMM (M=40960, N=128(80 used), K=512) ----------------
// grid 320 (m-blocks of 128, each within one batch b = blk/10, bt = blk/2, t5 = bt%5).
// B = wcomb[b]. Epilogue: c<40 -> pglob raw score; 40<=c<80 -> vascore; else discard.
__global__ __launch_bounds__(256) void gemm_sc(const u16* __restrict__ A,
                                               const u16* __restrict__ wcomb,
                                               float* __restrict__ pglob,
                                               float* __restrict__ vascore) {
    __shared__ u16 As[128][64];
    __shared__ u16 Bs[128][64];
    const int t = threadIdx.x;
    const int blk = blockIdx.x;
    const int bm0 = blk * 128;
    const int b = blk / 10;
    const int t5 = (blk >> 1) % 5;
    const u16* Bt = wcomb + (size_t)b * 128 * 512;
    const int wave = t >> 6, lane = t & 63;
    const int wm = (wave >> 1) * 64, wn = (wave & 1) * 64;
    const int lr = lane & 15, lh = lane >> 4;
    const int srow = wave * 8 + (lane >> 3);
    const int scol = (lane & 7) * 8;

    f32x4 acc[4][4] = {};

    for (int kt = 0; kt < 512; kt += 64) {
        __syncthreads();
#pragma unroll
        for (int i = 0; i < 4; i++) {
            int row = i * 32 + srow;
            int r = bm0 + row;
            long g = (long)(r >> 8) * 257 + (r & 255) + 1;   // V rows of x
            gl_lds16(&A[g * 512 + kt + scol], &As[0][0] + i * 2048 + wave * 512);
            gl_lds16(&Bt[(long)row * 512 + kt + scol], &Bs[0][0] + i * 2048 + wave * 512);
        }
        __syncthreads();
#pragma unroll
        for (int kk = 0; kk < 2; kk++) {
            bf16x8 af[4], bfr[4];
#pragma unroll
            for (int mi = 0; mi < 4; mi++)
                af[mi] = *(const bf16x8*)&As[wm + mi * 16 + lr][kk * 32 + lh * 8];
#pragma unroll
            for (int ni = 0; ni < 4; ni++)
                bfr[ni] = *(const bf16x8*)&Bs[wn + ni * 16 + lr][kk * 32 + lh * 8];
#pragma unroll
            for (int mi = 0; mi < 4; mi++)
#pragma unroll
                for (int ni = 0; ni < 4; ni++)
                    acc[mi][ni] = __builtin_amdgcn_mfma_f32_16x16x32_bf16(
                        af[mi], bfr[ni], acc[mi][ni], 0, 0, 0);
        }
    }

#pragma unroll
    for (int ni = 0; ni < 4; ni++) {
        const int c = wn + ni * 16 + lr;
        if (c < 40) {
            const int h = c / 5, q = c - h * 5;
            float* prow = &pglob[((size_t)(b * 8 + h) * 5 + q) * 1280];
#pragma unroll
            for (int mi = 0; mi < 4; mi++)
#pragma unroll
                for (int r2 = 0; r2 < 4; r2++) {
                    int m = bm0 + wm + mi * 16 + lh * 4 + r2;
                    int j = m & 255;
                    prow[j * 5 + t5] = acc[mi][ni][r2];
                }
        } else if (c < 80) {
#pragma unroll
            for (int mi = 0; mi < 4; mi++)
#pragma unroll
                for (int r2 = 0; r2 < 4; r2++) {
                    int m = bm0 + wm + mi * 16 + lh * 4 + r2;
                    vascore[(size_t)m * 40 + (c - 40)] = acc[mi][ni][r2];
                }
        }
    }
}

// ---------------- va_combine: per V-row softmax5 over heads -> cat V rows ----------------
// grid 160 (one bt each), 256 thr (thread = row j).
__global__ __launch_bounds__(256) void va_combine(const u16* __restrict__ aqkv,
                                                  const float* __restrict__ vascore,
                                                  const float* __restrict__ mask,
                                                  u16* __restrict__ cat) {
    __shared__ float vaL[5][512];
    __shared__ float pL[256][40];
    const int bt = blockIdx.x;
    const int b = bt / 5;
    const int t = threadIdx.x;
    for (int i = t; i < 2560; i += 256) {
        int q = i >> 9, c = i & 511;
        vaL[q][c] = bf2f(aqkv[(size_t)(b * 5 + q) * 1536 + 1024 + c]);
    }
    // per-row scores + softmax
    {
        const int j = t;
        const size_t m = (size_t)bt * 256 + j;
        float sc[40];
#pragma unroll
        for (int i = 0; i < 40; i += 4) {
            f32x4 s4 = *(const f32x4*)&vascore[m * 40 + i];
            sc[i] = s4[0]; sc[i + 1] = s4[1]; sc[i + 2] = s4[2]; sc[i + 3] = s4[3];
        }
        const float mval = mask[m] * 0.125f;
#pragma unroll
        for (int h = 0; h < 8; h++) {
            float r0 = sc[h * 5] * mval, r1 = sc[h * 5 + 1] * mval, r2 = sc[h * 5 + 2] * mval;
            float r3 = sc[h * 5 + 3] * mval, r4 = sc[h * 5 + 4] * mval;
            float mx = fmaxf(fmaxf(fmaxf(r0, r1), fmaxf(r2, r3)), r4);
            float e0 = __expf(r0 - mx), e1 = __expf(r1 - mx), e2 = __expf(r2 - mx);
            float e3 = __expf(r3 - mx), e4 = __expf(r4 - mx);
            float inv = 1.f / (e0 + e1 + e2 + e3 + e4);
            pL[j][h * 5]     = e0 * inv;
            pL[j][h * 5 + 1] = e1 * inv;
            pL[j][h * 5 + 2] = e2 * inv;
            pL[j][h * 5 + 3] = e3 * inv;
            pL[j][h * 5 + 4] = e4 * inv;
        }
    }
    __syncthreads();
    // output: cat[(bt*257 + 1 + rr)*512 + c]
    const size_t cbase = ((size_t)bt * 257 + 1) * 512;
    for (int i = t; i < 131072; i += 256) {
        int rr = i >> 9, c = i & 511;
        int h = c >> 6;
        float o = pL[rr][h * 5]     * vaL[0][c]
                + pL[rr][h * 5 + 1] * vaL[1][c]
                + pL[rr][h * 5 + 2] * vaL[2][c]
                + pL[rr][h * 5 + 3] * vaL[3][c]
                + pL[rr][h * 5 + 4] * vaL[4][c];
        cat[cbase + (size_t)rr * 512 + c] = f2bf(o);
    }
}

// ---------------- av_finish: softmax (in LDS) + PV + reduce + cat A rows ----------------
// grid 256 = (bi,hd); 512 threads = 8 waves. pglob holds RAW scores (x0.125 here).
__global__ __launch_bounds__(512) void av_finish(const u16* __restrict__ vv,
                                                 const float* __restrict__ pglob,
                                                 u16* __restrict__ cat) {
    __shared__ float pl[5][1280];
    __shared__ float pbuf[8][5][64];
    const int bh = blockIdx.x;
    const int bi = bh >> 3, hd = bh & 7;
    const int t = threadIdx.x;
    for (int i = t; i < 6400; i += 512) {
        pl[0][i] = pglob[(size_t)bh * 6400 + i] * 0.125f;
    }
    __syncthreads();
    const int wave = t >> 6, lane = t & 63;
    if (wave < 5) {
        float v[20];
        float mx = -3.4e38f;
#pragma unroll
        for (int i = 0; i < 20; i++) {
            v[i] = pl[wave][lane + i * 64];
            mx = fmaxf(mx, v[i]);
        }
#pragma unroll
        for (int off = 32; off > 0; off >>= 1) mx = fmaxf(mx, __shfl_xor(mx, off));
        float sum = 0.f;
#pragma unroll
        for (int i = 0; i < 20; i++) {
            v[i] = __expf(v[i] - mx);
            sum += v[i];
        }
#pragma unroll
        for (int off = 32; off > 0; off >>= 1) sum += __shfl_xor(sum, off);
        const float inv = 1.f / sum;
#pragma unroll
        for (int i = 0; i < 20; i++) pl[wave][lane + i * 64] = v[i] * inv;
    }
    __syncthreads();
    {
        float a0 = 0, a1 = 0, a2 = 0, a3 = 0, a4 = 0;
        const int j0 = wave * 32;
        for (int jj = 0; jj < 32; jj++) {
            const int j = j0 + jj;
#pragma unroll
            for (int t5 = 0; t5 < 5; t5++) {
                float v = bf2f(vv[(size_t)((bi * 5 + t5) * 256 + j) * 512 + hd * 64 + lane]);
                const int s = j * 5 + t5;
                a0 += pl[0][s] * v;
                a1 += pl[1][s] * v;
                a2 += pl[2][s] * v;
                a3 += pl[3][s] * v;
                a4 += pl[4][s] * v;
            }
        }
        pbuf[wave][0][lane] = a0;
        pbuf[wave][1][lane] = a1;
        pbuf[wave][2][lane] = a2;
        pbuf[wave][3][lane] = a3;
        pbuf[wave][4][lane] = a4;
    }
    __syncthreads();
    if (t < 320) {
        const int q = t >> 6, d = t & 63;
        float s = 0.f;
#pragma unroll
        for (int w = 0; w < 8; w++) s += pbuf[w][q][d];
        cat[(size_t)((bi * 5 + q) * 257) * 512 + hd * 64 + d] = f2bf(s);
    }
}

extern "C" void kernel_launch(void* const* d_in, const int* in_sizes, int n_in,
                              void* d_out, int out_size, void* d_ws, size_t ws_size,
                              hipStream_t stream) {
    const float* x    = (const float*)d_in[0];  // (160,257,512) f32
    const float* mask = (const float*)d_in[1];  // (160,256) f32
    const float* Wv   = (const float*)d_in[2];  // (512,1536) f32
    const float* Wa   = (const float*)d_in[3];  // (512,1536) f32
    const float* Wo   = (const float*)d_in[4];  // (512,512) f32
    const float* bo   = (const float*)d_in[5];  // (512,) f32
    float* out = (float*)d_out;

    char* ws = (char*)d_ws;
    u16*   xb      = (u16*)(ws);                  // 42,106,880
    u16*   WvTv    = (u16*)(ws + 42106880);       //    524,288
    u16*   WaT     = (u16*)(ws + 42631168);       //  1,572,864
    u16*   WoT     = (u16*)(ws + 44204032);       //    524,288
    u16*   aqkv    = (u16*)(ws + 44728320);       //    491,520
    u16*   wcomb   = (u16*)(ws + 45219840);       //  4,194,304  [32][128][512] bf16
    u16*   vv      = (u16*)(ws + 49414144);       // 41,943,040  [40960][512] bf16
    float* vascore = (float*)(ws + 91357184);     //  6,553,600  [40960][40] f32
    float* pglob   = (float*)(ws + 97910784);     //  6,553,600  [1280][1280] f32
    u16*   cat     = (u16*)(ws + 104464384);      // 42,106,880  -> ~146.6 MB

    prep<<<dim3(10600), 256, 0, stream>>>(x, Wv, Wa, Wo, xb, WvTv, WaT, WoT);

    // a_qkv = A @ Wa_qkv
    gemm_k<2, 0><<<dim3(12, 2), 256, 0, stream>>>(xb, WaT, aqkv, nullptr, 160, 1536, 512);

    // w-tilde vectors (reads Wv f32 + aqkv)
    wbuild<<<dim3(136), 512, 0, stream>>>(Wv, aqkv, wcomb);

    // vv = V @ Wv_v  (V-only projection, N=512)
    gemm_big<1, 0><<<dim3(2, 160), 1024, 0, stream>>>(xb, WvTv, vv, nullptr, 40960, 512);

    // scores: raw av -> pglob, raw va -> vascore
    gemm_sc<<<dim3(320), 256, 0, stream>>>(xb, wcomb, pglob, vascore);

    // va: softmax5 + combine with va vectors -> cat V rows
    va_combine<<<dim3(160), 256, 0, stream>>>(aqkv, vascore, mask, cat);

    // av: softmax + PV + reduce -> cat A rows
    av_finish<<<dim3(256), 512, 0, stream>>>(vv, pglob, cat);

    // out = cat @ Wo + bo
    gemm_big<0, 1><<<dim3(2, 161), 1024, 0, stream>>>(cat, WoT, out, bo, 41120, 512);
}

// Round 15
// 227.217 us; speedup vs baseline: 1.0697x; 1.0697x over previous
//
#include <hip/hip_runtime.h>
#include <hip/hip_bf16.h>

typedef unsigned short u16;
typedef __bf16 bf16x8 __attribute__((ext_vector_type(8)));
typedef u16 u16x8 __attribute__((ext_vector_type(8)));
typedef float f32x4 __attribute__((ext_vector_type(4)));

__device__ __forceinline__ float bf2f(u16 u) {
    return __uint_as_float(((unsigned)u) << 16);
}
__device__ __forceinline__ u16 f2bf(float f) {
    unsigned u = __float_as_uint(f);
    unsigned r = (u + 0x7fffu + ((u >> 16) & 1u)) >> 16;
    return (u16)r;
}

// async global->LDS, 16B per lane. dst is wave-uniform base; HW adds lane*16.
__device__ __forceinline__ void gl_lds16(const u16* g, u16* l) {
    __builtin_amdgcn_global_load_lds(
        (const __attribute__((address_space(1))) void*)g,
        (__attribute__((address_space(3))) void*)l, 16, 0, 0);
}

// ---------------- fused prep: x f32->bf16 convert + 3 weight transposes ----------------
// blocks [0,10280): convert x; [10280,+64): WvTv (Wv cols 1024:1536);
// [+64,+256): WaT; [+256,+320): WoT.
__global__ __launch_bounds__(256) void prep(const float* __restrict__ x,
                                            const float* __restrict__ Wv,
                                            const float* __restrict__ Wa,
                                            const float* __restrict__ Wo,
                                            u16* __restrict__ xb,
                                            u16* __restrict__ WvTv,
                                            u16* __restrict__ WaT,
                                            u16* __restrict__ WoT) {
    __shared__ float tile[64][65];
    int blk = blockIdx.x;
    if (blk < 10280) {
        int i = (blk * 256 + threadIdx.x) * 8;
        float4 a = *(const float4*)&x[i];
        float4 b = *(const float4*)&x[i + 4];
        u16x8 o;
        o[0] = f2bf(a.x); o[1] = f2bf(a.y); o[2] = f2bf(a.z); o[3] = f2bf(a.w);
        o[4] = f2bf(b.x); o[5] = f2bf(b.y); o[6] = f2bf(b.z); o[7] = f2bf(b.w);
        *(u16x8*)&xb[i] = o;
        return;
    }
    blk -= 10280;
    const float* W; u16* WT; int N, stride, coff;
    if (blk < 64)       { W = Wv; WT = WvTv; N = 512;  stride = 1536; coff = 1024; }
    else if (blk < 256) { W = Wa; WT = WaT;  N = 1536; stride = 1536; coff = 0; blk -= 64; }
    else                { W = Wo; WT = WoT;  N = 512;  stride = 512;  coff = 0; blk -= 256; }
    const int nt = N >> 6;
    const int k0 = (blk / nt) << 6;
    const int n0 = (blk % nt) << 6;
    for (int i = threadIdx.x; i < 4096; i += 256) {
        int r = i >> 6, c = i & 63;
        tile[r][c] = W[(size_t)(k0 + r) * stride + coff + n0 + c];
    }
    __syncthreads();
    for (int i = threadIdx.x; i < 4096; i += 256) {
        int r = i >> 6, c = i & 63;
        WT[(size_t)(n0 + r) * 512 + k0 + c] = f2bf(tile[c][r]);
    }
}

// ---------------- small m97-style GEMM (A-projection) ----------
// MODE 2: row r -> r*257 (clamp r<M).
template <int MODE, int OUTF>
__global__ __launch_bounds__(256) void gemm_k(const u16* __restrict__ A,
                                              const u16* __restrict__ Bt,
                                              void* __restrict__ Cv,
                                              const float* __restrict__ bias,
                                              int M, int N, int K) {
    __shared__ u16 As[128][64];
    __shared__ u16 Bs[128][64];
    const int t = threadIdx.x;
    const int bn0 = blockIdx.x * 128;
    const int bm0 = blockIdx.y * 128;
    const int wave = t >> 6, lane = t & 63;
    const int wm = (wave >> 1) * 64, wn = (wave & 1) * 64;
    const int lr = lane & 15, lh = lane >> 4;
    const int srow = wave * 8 + (lane >> 3);
    const int scol = (lane & 7) * 8;

    f32x4 acc[4][4] = {};

    for (int kt = 0; kt < K; kt += 64) {
        __syncthreads();
#pragma unroll
        for (int i = 0; i < 4; i++) {
            int row = i * 32 + srow;
            int r = bm0 + row;
            long g;
            if (MODE == 0) g = (r < M) ? (long)r : 0l;
            else           g = (r < M) ? (long)r * 257 : 0l;
            gl_lds16(&A[g * K + kt + scol], &As[0][0] + i * 2048 + wave * 512);
            long nr = bn0 + row;
            gl_lds16(&Bt[nr * K + kt + scol], &Bs[0][0] + i * 2048 + wave * 512);
        }
        __syncthreads();
#pragma unroll
        for (int kk = 0; kk < 2; kk++) {
            bf16x8 af[4], bfr[4];
#pragma unroll
            for (int mi = 0; mi < 4; mi++)
                af[mi] = *(const bf16x8*)&As[wm + mi * 16 + lr][kk * 32 + lh * 8];
#pragma unroll
            for (int ni = 0; ni < 4; ni++)
                bfr[ni] = *(const bf16x8*)&Bs[wn + ni * 16 + lr][kk * 32 + lh * 8];
#pragma unroll
            for (int mi = 0; mi < 4; mi++)
#pragma unroll
                for (int ni = 0; ni < 4; ni++)
                    acc[mi][ni] = __builtin_amdgcn_mfma_f32_16x16x32_bf16(
                        af[mi], bfr[ni], acc[mi][ni], 0, 0, 0);
        }
    }

#pragma unroll
    for (int mi = 0; mi < 4; mi++)
#pragma unroll
        for (int ni = 0; ni < 4; ni++)
#pragma unroll
            for (int r2 = 0; r2 < 4; r2++) {
                int m = bm0 + wm + mi * 16 + lh * 4 + r2;
                if (m < M) {
                    int nc = bn0 + wn + ni * 16 + lr;
                    float v = acc[mi][ni][r2];
                    if (OUTF) ((float*)Cv)[(size_t)m * N + nc] = v + bias[nc];
                    else      ((u16*)Cv)[(size_t)m * N + nc] = f2bf(v);
                }
            }
}

// ---------------- pipelined 256x256 GEMM, K=512 (rounds 11-13 verified) ----------------
template <int MODE, int OUTF>
__global__ __launch_bounds__(1024) void gemm_big(const u16* __restrict__ A,
                                                 const u16* __restrict__ Bt,
                                                 void* __restrict__ Cv,
                                                 const float* __restrict__ bias,
                                                 int M, int N) {
    __shared__ u16 As[2][256][64];
    __shared__ u16 Bs[2][256][64];
    const int t = threadIdx.x;
    const int nwg = gridDim.x * gridDim.y;
    const int orig = blockIdx.y * gridDim.x + blockIdx.x;
    const int qc = nwg >> 3, rc = nwg & 7;
    const int xcd = orig & 7, slot = orig >> 3;
    const int wgid = (xcd < rc ? xcd * (qc + 1) : rc * (qc + 1) + (xcd - rc) * qc) + slot;
    const int bn0 = (wgid % gridDim.x) * 256;
    const int bm0 = (wgid / gridDim.x) * 256;
    const int wave = t >> 6, lane = t & 63;
    const int wm = (wave >> 2) * 64, wn = (wave & 3) * 64;
    const int lr = lane & 15, lh = lane >> 4;
    const int xr = (lr & 7) << 3;
    u16* AsF = &As[0][0][0];
    u16* BsF = &Bs[0][0][0];

    const int gsa = ((lane & 7) ^ (lane >> 3)) * 8;
    auto stage = [&](int buf, int kt_) {
        const int kc = kt_ * 64;
#pragma unroll
        for (int j = 0; j < 2; j++) {
            int c0 = j * 1024 + wave * 64;
            int row = (c0 + lane) >> 3;
            int r = bm0 + row;
            long ga;
            if (MODE == 0) ga = (r < M) ? (long)r : 0l;
            else           ga = (long)(r >> 8) * 257 + (r & 255) + 1;
            gl_lds16(&A[ga * 512 + kc + gsa], AsF + buf * 16384 + c0 * 8);
            gl_lds16(&Bt[(long)(bn0 + row) * 512 + kc + gsa], BsF + buf * 16384 + c0 * 8);
        }
    };

    f32x4 acc[4][4] = {};

    stage(0, 0);
    __builtin_amdgcn_sched_barrier(0);
    stage(1, 1);
    __builtin_amdgcn_sched_barrier(0);
    asm volatile("s_waitcnt vmcnt(0)" ::: "memory");
    __builtin_amdgcn_s_barrier();
    __builtin_amdgcn_sched_barrier(0);

    int cur = 0;
    for (int kt = 0; kt < 8; kt++) {
        __builtin_amdgcn_s_setprio(1);
#pragma unroll
        for (int kk = 0; kk < 2; kk++) {
            bf16x8 af[4], bfr[4];
#pragma unroll
            for (int mi = 0; mi < 4; mi++)
                af[mi] = *(const bf16x8*)&As[cur][wm + mi * 16 + lr][(kk * 32 + lh * 8) ^ xr];
#pragma unroll
            for (int ni = 0; ni < 4; ni++)
                bfr[ni] = *(const bf16x8*)&Bs[cur][wn + ni * 16 + lr][(kk * 32 + lh * 8) ^ xr];
#pragma unroll
            for (int mi = 0; mi < 4; mi++)
#pragma unroll
                for (int ni = 0; ni < 4; ni++)
                    acc[mi][ni] = __builtin_amdgcn_mfma_f32_16x16x32_bf16(
                        af[mi], bfr[ni], acc[mi][ni], 0, 0, 0);
        }
        __builtin_amdgcn_s_setprio(0);
        if (kt == 7) break;
        __builtin_amdgcn_sched_barrier(0);
        __builtin_amdgcn_s_barrier();
        __builtin_amdgcn_sched_barrier(0);
        if (kt + 2 < 8) {
            stage(cur, kt + 2);
            __builtin_amdgcn_sched_barrier(0);
            asm volatile("s_waitcnt vmcnt(4)" ::: "memory");
        } else {
            asm volatile("s_waitcnt vmcnt(0)" ::: "memory");
        }
        __builtin_amdgcn_sched_barrier(0);
        __builtin_amdgcn_s_barrier();
        __builtin_amdgcn_sched_barrier(0);
        cur ^= 1;
    }

#pragma unroll
    for (int mi = 0; mi < 4; mi++)
#pragma unroll
        for (int ni = 0; ni < 4; ni++)
#pragma unroll
            for (int r2 = 0; r2 < 4; r2++) {
                int m = bm0 + wm + mi * 16 + lh * 4 + r2;
                if (m < M) {
                    int nc = bn0 + wn + ni * 16 + lr;
                    float v = acc[mi][ni][r2];
                    if (OUTF) ((float*)Cv)[(size_t)m * N + nc] = v + bias[nc];
                    else      ((u16*)Cv)[(size_t)m * N + nc] = f2bf(v);
                }
            }
}

// ---------------- wbuild: w-tilde vectors ----------------
// wcomb[b][c][k], c = kind*40 + h*5 + q (rows 80..127 zero-padded).
// kind 0 (av): w = Wk_head @ qa  (Wv cols 512+h*64, aqkv off 0)
// kind 1 (va): w = Wq_head @ ka  (Wv cols h*64,     aqkv off 512)
// grid 136: blk<128 compute (kind=blk&1, h=(blk>>1)&7, vchunk=blk>>4); else pad-zero.
__global__ __launch_bounds__(512) void wbuild(const float* __restrict__ Wv,
                                              const u16* __restrict__ aqkv,
                                              u16* __restrict__ wcomb) {
    const int blk = blockIdx.x;
    const int t = threadIdx.x;
    if (blk >= 128) {
        const int base = blk - 128;          // 0..7 -> 4 b's each
        for (int bb = 0; bb < 4; bb++) {
            int b = base * 4 + bb;
            for (int i = t; i < 24576; i += 512)          // rows 80..127 contiguous
                wcomb[((size_t)b * 128 + 80) * 512 + i] = 0;
        }
        return;
    }
    __shared__ float avec[20][64];
    const int kind = blk & 1, h = (blk >> 1) & 7, vc = blk >> 4;
    const int v0 = vc * 20;
    const int aoff = (kind == 0) ? 0 : 512;
    for (int i = t; i < 1280; i += 512) {
        int vi = i >> 6, d = i & 63;
        int v = v0 + vi, b = v / 5, q = v - b * 5;
        avec[vi][d] = bf2f(aqkv[(size_t)(b * 5 + q) * 1536 + aoff + h * 64 + d]);
    }
    const int k = t;                                       // 0..511
    const int colbase = (kind == 0) ? (512 + h * 64) : (h * 64);
    float wr[64];
#pragma unroll
    for (int d = 0; d < 64; d += 4) {
        float4 w4 = *(const float4*)&Wv[(size_t)k * 1536 + colbase + d];
        wr[d] = w4.x; wr[d + 1] = w4.y; wr[d + 2] = w4.z; wr[d + 3] = w4.w;
    }
    __syncthreads();
    for (int vi = 0; vi < 20; vi++) {
        float acc = 0.f;
#pragma unroll
        for (int d = 0; d < 64; d++) acc += wr[d] * avec[vi][d];
        int v = v0 + vi, b = v / 5, q = v - b * 5;
        int c = kind * 40 + h * 5 + q;
        wcomb[((size_t)b * 128 + c) * 512 + k] = f2bf(acc);
    }
}

// ---------------- gemm_sc: scores GEMM (M=40960, N=128(80 used), K=512) ----------------
// grid 320 (m-blocks of 128, each within one batch b = blk/10, bt = blk/2, t5 = bt%5).
// B = wcomb[b]. Epilogue: c<40 -> pglob raw score; 40<=c<80 -> vascore; else discard.
__global__ __launch_bounds__(256) void gemm_sc(const u16* __restrict__ A,
                                               const u16* __restrict__ wcomb,
                                               float* __restrict__ pglob,
                                               float* __restrict__ vascore) {
    __shared__ u16 As[128][64];
    __shared__ u16 Bs[128][64];
    const int t = threadIdx.x;
    const int blk = blockIdx.x;
    const int bm0 = blk * 128;
    const int b = blk / 10;
    const int t5 = (blk >> 1) % 5;
    const u16* Bt = wcomb + (size_t)b * 128 * 512;
    const int wave = t >> 6, lane = t & 63;
    const int wm = (wave >> 1) * 64, wn = (wave & 1) * 64;
    const int lr = lane & 15, lh = lane >> 4;
    const int srow = wave * 8 + (lane >> 3);
    const int scol = (lane & 7) * 8;

    f32x4 acc[4][4] = {};

    for (int kt = 0; kt < 512; kt += 64) {
        __syncthreads();
#pragma unroll
        for (int i = 0; i < 4; i++) {
            int row = i * 32 + srow;
            int r = bm0 + row;
            long g = (long)(r >> 8) * 257 + (r & 255) + 1;   // V rows of x
            gl_lds16(&A[g * 512 + kt + scol], &As[0][0] + i * 2048 + wave * 512);
            gl_lds16(&Bt[(long)row * 512 + kt + scol], &Bs[0][0] + i * 2048 + wave * 512);
        }
        __syncthreads();
#pragma unroll
        for (int kk = 0; kk < 2; kk++) {
            bf16x8 af[4], bfr[4];
#pragma unroll
            for (int mi = 0; mi < 4; mi++)
                af[mi] = *(const bf16x8*)&As[wm + mi * 16 + lr][kk * 32 + lh * 8];
#pragma unroll
            for (int ni = 0; ni < 4; ni++)
                bfr[ni] = *(const bf16x8*)&Bs[wn + ni * 16 + lr][kk * 32 + lh * 8];
#pragma unroll
            for (int mi = 0; mi < 4; mi++)
#pragma unroll
                for (int ni = 0; ni < 4; ni++)
                    acc[mi][ni] = __builtin_amdgcn_mfma_f32_16x16x32_bf16(
                        af[mi], bfr[ni], acc[mi][ni], 0, 0, 0);
        }
    }

#pragma unroll
    for (int ni = 0; ni < 4; ni++) {
        const int c = wn + ni * 16 + lr;
        if (c < 40) {
            const int h = c / 5, q = c - h * 5;
            float* prow = &pglob[((size_t)(b * 8 + h) * 5 + q) * 1280];
#pragma unroll
            for (int mi = 0; mi < 4; mi++)
#pragma unroll
                for (int r2 = 0; r2 < 4; r2++) {
                    int m = bm0 + wm + mi * 16 + lh * 4 + r2;
                    int j = m & 255;
                    prow[j * 5 + t5] = acc[mi][ni][r2];
                }
        } else if (c < 80) {
#pragma unroll
            for (int mi = 0; mi < 4; mi++)
#pragma unroll
                for (int r2 = 0; r2 < 4; r2++) {
                    int m = bm0 + wm + mi * 16 + lh * 4 + r2;
                    vascore[(size_t)m * 40 + (c - 40)] = acc[mi][ni][r2];
                }
        }
    }
}

// ---------------- va_combine: block-per-(bt,head), va in registers ----------------
// grid 1280 = bt(160) x h(8); 256 thr = 4 waves; lane = d, wave strides rows.
__global__ __launch_bounds__(256) void va_combine(const u16* __restrict__ aqkv,
                                                  const float* __restrict__ vascore,
                                                  const float* __restrict__ mask,
                                                  u16* __restrict__ cat) {
    const int blk = blockIdx.x;
    const int bt = blk >> 3, h = blk & 7;
    const int b = bt / 5;
    const int wave = threadIdx.x >> 6, lane = threadIdx.x & 63;
    float va5[5];
#pragma unroll
    for (int q = 0; q < 5; q++)
        va5[q] = bf2f(aqkv[(size_t)(b * 5 + q) * 1536 + 1024 + h * 64 + lane]);
    const size_t cbase = ((size_t)bt * 257 + 1) * 512 + h * 64;
    for (int rr = wave; rr < 256; rr += 4) {
        const size_t m = (size_t)bt * 256 + rr;
        const float mval = mask[m] * 0.125f;
        const float* sp = &vascore[m * 40 + h * 5];
        float r0 = sp[0] * mval, r1 = sp[1] * mval, r2 = sp[2] * mval;
        float r3 = sp[3] * mval, r4 = sp[4] * mval;
        float mx = fmaxf(fmaxf(fmaxf(r0, r1), fmaxf(r2, r3)), r4);
        float e0 = __expf(r0 - mx), e1 = __expf(r1 - mx), e2 = __expf(r2 - mx);
        float e3 = __expf(r3 - mx), e4 = __expf(r4 - mx);
        const float inv = 1.f / (e0 + e1 + e2 + e3 + e4);
        float o = (e0 * va5[0] + e1 * va5[1] + e2 * va5[2] + e3 * va5[3] + e4 * va5[4]) * inv;
        cat[cbase + (size_t)rr * 512 + lane] = f2bf(o);
    }
}

// ---------------- av_finish: softmax (in LDS) + PV + reduce + cat A rows ----------------
// grid 256 = (bi,hd); 512 threads = 8 waves. pglob holds RAW scores (x0.125 here).
__global__ __launch_bounds__(512) void av_finish(const u16* __restrict__ vv,
                                                 const float* __restrict__ pglob,
                                                 u16* __restrict__ cat) {
    __shared__ float pl[5][1280];
    __shared__ float pbuf[8][5][64];
    const int bh = blockIdx.x;
    const int bi = bh >> 3, hd = bh & 7;
    const int t = threadIdx.x;
    for (int i = t; i < 6400; i += 512) {
        pl[0][i] = pglob[(size_t)bh * 6400 + i] * 0.125f;
    }
    __syncthreads();
    const int wave = t >> 6, lane = t & 63;
    if (wave < 5) {
        float v[20];
        float mx = -3.4e38f;
#pragma unroll
        for (int i = 0; i < 20; i++) {
            v[i] = pl[wave][lane + i * 64];
            mx = fmaxf(mx, v[i]);
        }
#pragma unroll
        for (int off = 32; off > 0; off >>= 1) mx = fmaxf(mx, __shfl_xor(mx, off));
        float sum = 0.f;
#pragma unroll
        for (int i = 0; i < 20; i++) {
            v[i] = __expf(v[i] - mx);
            sum += v[i];
        }
#pragma unroll
        for (int off = 32; off > 0; off >>= 1) sum += __shfl_xor(sum, off);
        const float inv = 1.f / sum;
#pragma unroll
        for (int i = 0; i < 20; i++) pl[wave][lane + i * 64] = v[i] * inv;
    }
    __syncthreads();
    {
        float a0 = 0, a1 = 0, a2 = 0, a3 = 0, a4 = 0;
        const int j0 = wave * 32;
        for (int jj = 0; jj < 32; jj++) {
            const int j = j0 + jj;
#pragma unroll
            for (int t5 = 0; t5 < 5; t5++) {
                float v = bf2f(vv[(size_t)((bi * 5 + t5) * 256 + j) * 512 + hd * 64 + lane]);
                const int s = j * 5 + t5;
                a0 += pl[0][s] * v;
                a1 += pl[1][s] * v;
                a2 += pl[2][s] * v;
                a3 += pl[3][s] * v;
                a4 += pl[4][s] * v;
            }
        }
        pbuf[wave][0][lane] = a0;
        pbuf[wave][1][lane] = a1;
        pbuf[wave][2][lane] = a2;
        pbuf[wave][3][lane] = a3;
        pbuf[wave][4][lane] = a4;
    }
    __syncthreads();
    if (t < 320) {
        const int q = t >> 6, d = t & 63;
        float s = 0.f;
#pragma unroll
        for (int w = 0; w < 8; w++) s += pbuf[w][q][d];
        cat[(size_t)((bi * 5 + q) * 257) * 512 + hd * 64 + d] = f2bf(s);
    }
}

extern "C" void kernel_launch(void* const* d_in, const int* in_sizes, int n_in,
                              void* d_out, int out_size, void* d_ws, size_t ws_size,
                              hipStream_t stream) {
    const float* x    = (const float*)d_in[0];  // (160,257,512) f32
    const float* mask = (const float*)d_in[1];  // (160,256) f32
    const float* Wv   = (const float*)d_in[2];  // (512,1536) f32
    const float* Wa   = (const float*)d_in[3];  // (512,1536) f32
    const float* Wo   = (const float*)d_in[4];  // (512,512) f32
    const float* bo   = (const float*)d_in[5];  // (512,) f32
    float* out = (float*)d_out;

    char* ws = (char*)d_ws;
    u16*   xb      = (u16*)(ws);                  // 42,106,880
    u16*   WvTv    = (u16*)(ws + 42106880);       //    524,288
    u16*   WaT     = (u16*)(ws + 42631168);       //  1,572,864
    u16*   WoT     = (u16*)(ws + 44204032);       //    524,288
    u16*   aqkv    = (u16*)(ws + 44728320);       //    491,520
    u16*   wcomb   = (u16*)(ws + 45219840);       //  4,194,304  [32][128][512] bf16
    u16*   vv      = (u16*)(ws + 49414144);       // 41,943,040  [40960][512] bf16
    float* vascore = (float*)(ws + 91357184);     //  6,553,600  [40960][40] f32
    float* pglob   = (float*)(ws + 97910784);     //  6,553,600  [1280][1280] f32
    u16*   cat     = (u16*)(ws + 104464384);      // 42,106,880  -> ~146.6 MB

    prep<<<dim3(10600), 256, 0, stream>>>(x, Wv, Wa, Wo, xb, WvTv, WaT, WoT);

    // a_qkv = A @ Wa_qkv
    gemm_k<2, 0><<<dim3(12, 2), 256, 0, stream>>>(xb, WaT, aqkv, nullptr, 160, 1536, 512);

    // w-tilde vectors (reads Wv f32 + aqkv)
    wbuild<<<dim3(136), 512, 0, stream>>>(Wv, aqkv, wcomb);

    // vv = V @ Wv_v  (V-only projection, N=512)
    gemm_big<1, 0><<<dim3(2, 160), 1024, 0, stream>>>(xb, WvTv, vv, nullptr, 40960, 512);

    // scores: raw av -> pglob, raw va -> vascore
    gemm_sc<<<dim3(320), 256, 0, stream>>>(xb, wcomb, pglob, vascore);

    // va: softmax5 + combine with va vectors -> cat V rows
    va_combine<<<dim3(1280), 256, 0, stream>>>(aqkv, vascore, mask, cat);

    // av: softmax + PV + reduce -> cat A rows
    av_finish<<<dim3(256), 512, 0, stream>>>(vv, pglob, cat);

    // out = cat @ Wo + bo
    gemm_big<0, 1><<<dim3(2, 161), 1024, 0, stream>>>(cat, WoT, out, bo, 41120, 512);
}